// Round 1
// baseline (9784.621 us; speedup 1.0000x reference)
//
#include <hip/hip_runtime.h>
#include <math.h>

typedef _Float16 f16;
typedef _Float16 f16x8 __attribute__((ext_vector_type(8)));
typedef _Float16 f16x4 __attribute__((ext_vector_type(4)));
typedef float f32x4 __attribute__((ext_vector_type(4)));

#define B_ 32
#define T_ 1024
#define I_ 128
#define H_ 512

#define NWG 48
#define NWG_A 16

// workspace layout (bytes)
#define OFF_FLAGS 0UL
#define OFF_H1    4096UL               // f16 [2][32][512]  = 65536
#define OFF_H2    69632UL              // f16 [2][32][512]  = 65536
#define OFF_XT    147456UL             // f16 [1024][32][128] = 8388608
#define OFF_H2S   8536064UL            // f32 [32][1024][512] = 67108864
#define OFF_O1    75644928UL           // f32 [32768][128]    = 16777216
// total ws needed: 92,422,144 bytes

__device__ inline f32x4 mfma16(f16x8 a, f16x8 b, f32x4 c) {
  return __builtin_amdgcn_mfma_f32_16x16x32_f16(a, b, c, 0, 0, 0);
}
__device__ inline float fast_sig(float x) { return 1.f / (1.f + __expf(-x)); }
__device__ inline float fast_tanh(float x) {
  float e = __expf(-2.f * fabsf(x));
  float t = (1.f - e) / (1.f + e);
  return x < 0.f ? -t : t;
}

// Flag-array grid barrier: one release store per WG (padded, no RMW contention),
// wave-0 gathers all 48 flags in a single 64-lane load. Monotone targets.
__device__ inline void grid_barrier(unsigned* flags, int wg, unsigned target) {
  __syncthreads();                       // compiler emits vmcnt(0) drain before s_barrier
  if (threadIdx.x == 0) {
    __hip_atomic_store(flags + wg * 4, target, __ATOMIC_RELEASE, __HIP_MEMORY_SCOPE_AGENT);
  }
  if (threadIdx.x < 64) {
    const int l = threadIdx.x;
    for (;;) {
      unsigned v = (l < NWG)
          ? __hip_atomic_load(flags + l * 4, __ATOMIC_RELAXED, __HIP_MEMORY_SCOPE_AGENT)
          : target;
      if (__all((int)(v >= target))) break;
      __builtin_amdgcn_s_sleep(2);
    }
    __threadfence();                     // acquire: invalidate L1/L2 before reading remote h
  }
  __syncthreads();
}

// x[b][t][i] f32 -> xT[t][b][i] f16
__global__ __launch_bounds__(256) void prep_xT(const float* __restrict__ x, f16* __restrict__ xT) {
  const int idx = blockIdx.x * 256 + threadIdx.x;
  const int n4 = B_ * T_ * I_ / 4;
  if (idx < n4) {
    const int i4 = idx * 4;
    const int i  = i4 & (I_ - 1);
    const int tt = (i4 >> 7) & (T_ - 1);
    const int b  = i4 >> 17;
    float4 v = *(const float4*)(x + i4);
    f16x4 o;
    o[0] = (f16)v.x; o[1] = (f16)v.y; o[2] = (f16)v.z; o[3] = (f16)v.w;
    *(f16x4*)(xT + ((size_t)tt * B_ + b) * I_ + i) = o;
  }
}

// Persistent pipelined 2-layer LSTM.
// WGs 0..15  (A): layer 0, 32 h-cols each, K=640  ([x_t | h1_{t-1}])
// WGs 16..47 (B): layer 1, 16 h-cols each, K=1024 ([h1_t | h2_{t-1}]), lags A by 1 step.
// Weights live in VGPRs (per-wave MFMA B-fragments), loaded once.
__global__ __launch_bounds__(512) void lstm_persist(
    const float* __restrict__ Wih0, const float* __restrict__ Whh0,
    const float* __restrict__ bih0, const float* __restrict__ bhh0,
    const float* __restrict__ Wih1, const float* __restrict__ Whh1,
    const float* __restrict__ bih1, const float* __restrict__ bhh1,
    const f16* __restrict__ xT, f16* h1buf, f16* h2buf, float* h2seq,
    unsigned* flags) {
  __shared__ float gbuf[4160];   // A: [32][129] gate tiles; B: [2][32][65]
  __shared__ float bias_l[128];

  const int tid  = threadIdx.x;
  const int wg   = blockIdx.x;
  const int lane = tid & 63;
  const int wv   = tid >> 6;     // 0..7
  const int cfr  = lane & 15;    // fragment col / row-in-tile
  const int ksub = lane >> 4;    // 0..3 (k sub-block of 8)

  if (wg < NWG_A) {
    // ---------------- layer 0 ----------------
    const int wgA = wg;
    if (tid < 128) {
      const int g = tid >> 5, hc = tid & 31;
      const int row = g * 512 + wgA * 32 + hc;
      bias_l[tid] = bih0[row] + bhh0[row];
    }
    const int mt = wv & 1;       // batch tile (0: b0-15, 1: b16-31)
    const int np = wv >> 1;      // ntile pair 0..3 (gate-col pairs)
    // W fragments -> registers (2 ntiles x 20 ksteps)
    f16x8 wr0[20], wr1[20];
#pragma unroll
    for (int nti = 0; nti < 2; ++nti) {
      const int nt  = np * 2 + nti;
      const int gc  = nt * 16 + cfr;
      const int g   = gc >> 5;
      const int hcc = gc & 31;
      const int row = g * 512 + wgA * 32 + hcc;
#pragma unroll
      for (int ks = 0; ks < 20; ++ks) {
        const int k = ks * 32 + ksub * 8;
        const float* src = (k < I_) ? (Wih0 + (size_t)row * I_ + k)
                                    : (Whh0 + (size_t)row * H_ + (k - I_));
        float4 v0 = *(const float4*)(src);
        float4 v1 = *(const float4*)(src + 4);
        f16x8 h;
        h[0] = (f16)v0.x; h[1] = (f16)v0.y; h[2] = (f16)v0.z; h[3] = (f16)v0.w;
        h[4] = (f16)v1.x; h[5] = (f16)v1.y; h[6] = (f16)v1.z; h[7] = (f16)v1.w;
        if (nti == 0) wr0[ks] = h; else wr1[ks] = h;
      }
    }
    float cst0 = 0.f, cst1 = 0.f;          // cell state: pairs (rb,rh),(rb,rh+16)
    const int rb = tid & 31;
    const int rh = tid >> 5;               // 0..15
    const int bi = mt * 16 + cfr;
    const int colb = np * 32 + cfr;
    __syncthreads();

    for (int s = 0; s <= T_; ++s) {
      if (s < T_) {
        f32x4 acc0 = {0.f, 0.f, 0.f, 0.f}, acc1 = {0.f, 0.f, 0.f, 0.f};
        const f16* xb = xT + ((size_t)s * B_ + bi) * I_ + ksub * 8;
        const f16* hb = h1buf + (size_t)((s + 1) & 1) * (B_ * H_) + (size_t)bi * H_ + ksub * 8;
#pragma unroll
        for (int ks = 0; ks < 4; ++ks) {
          f16x8 af = *(const f16x8*)(xb + ks * 32);
          acc0 = mfma16(af, wr0[ks], acc0);
          acc1 = mfma16(af, wr1[ks], acc1);
        }
#pragma unroll
        for (int ks = 4; ks < 20; ++ks) {
          f16x8 af = *(const f16x8*)(hb + (ks - 4) * 32);
          acc0 = mfma16(af, wr0[ks], acc0);
          acc1 = mfma16(af, wr1[ks], acc1);
        }
        const int rowb = mt * 16 + ksub * 4;
#pragma unroll
        for (int r = 0; r < 4; ++r) {
          gbuf[(rowb + r) * 129 + colb]      = acc0[r];
          gbuf[(rowb + r) * 129 + colb + 16] = acc1[r];
        }
      }
      __syncthreads();
      if (s < T_) {
        f16* h1o = h1buf + (size_t)(s & 1) * (B_ * H_);
#pragma unroll
        for (int pp = 0; pp < 2; ++pp) {
          const int hc = rh + pp * 16;
          const float pi = gbuf[rb * 129 +      hc] + bias_l[     hc];
          const float pf = gbuf[rb * 129 + 32 + hc] + bias_l[32 + hc];
          const float pg = gbuf[rb * 129 + 64 + hc] + bias_l[64 + hc];
          const float po = gbuf[rb * 129 + 96 + hc] + bias_l[96 + hc];
          const float ig = fast_sig(pi);
          const float fg = fast_sig(pf);
          const float gg = fast_tanh(pg);
          const float og = fast_sig(po);
          const float cprev = pp ? cst1 : cst0;
          const float cnew = fg * cprev + ig * gg;
          if (pp) cst1 = cnew; else cst0 = cnew;
          const float hv = og * fast_tanh(cnew);
          h1o[(size_t)rb * H_ + wgA * 32 + hc] = (f16)hv;
        }
      }
      grid_barrier(flags, wg, (unsigned)(s + 1));
    }
  } else {
    // ---------------- layer 1 (lags by 1 step) ----------------
    const int wgB = wg - NWG_A;            // 0..31
    if (tid < 64) {
      const int g = tid >> 4, hc = tid & 15;
      const int row = g * 512 + wgB * 16 + hc;
      bias_l[tid] = bih1[row] + bhh1[row];
    }
    const int mt = wv & 1;
    const int kh = (wv >> 1) & 1;          // K half: 0 -> h1_t, 1 -> h2_{t-1}
    const int np = wv >> 2;                // 0..1
    f16x8 wr0[16], wr1[16];
#pragma unroll
    for (int nti = 0; nti < 2; ++nti) {
      const int nt  = np * 2 + nti;
      const int gc  = nt * 16 + cfr;
      const int g   = gc >> 4;
      const int hcc = gc & 15;
      const int row = g * 512 + wgB * 16 + hcc;
#pragma unroll
      for (int kl = 0; kl < 16; ++kl) {
        const int k = (kh * 16 + kl) * 32 + ksub * 8;
        const float* src = (k < H_) ? (Wih1 + (size_t)row * H_ + k)
                                    : (Whh1 + (size_t)row * H_ + (k - H_));
        float4 v0 = *(const float4*)(src);
        float4 v1 = *(const float4*)(src + 4);
        f16x8 h;
        h[0] = (f16)v0.x; h[1] = (f16)v0.y; h[2] = (f16)v0.z; h[3] = (f16)v0.w;
        h[4] = (f16)v1.x; h[5] = (f16)v1.y; h[6] = (f16)v1.z; h[7] = (f16)v1.w;
        if (nti == 0) wr0[kl] = h; else wr1[kl] = h;
      }
    }
    float cst = 0.f;
    const int rb = tid & 31;
    const int rh = (tid >> 5) & 15;
    const int bi = mt * 16 + cfr;
    const int colb = np * 32 + cfr;
    __syncthreads();

    for (int s = 0; s <= T_; ++s) {
      const int t = s - 1;
      if (s >= 1) {
        f32x4 acc0 = {0.f, 0.f, 0.f, 0.f}, acc1 = {0.f, 0.f, 0.f, 0.f};
        const f16* sh = (kh == 0)
            ? (h1buf + (size_t)(t & 1) * (B_ * H_) + (size_t)bi * H_ + ksub * 8)
            : (h2buf + (size_t)((t + 1) & 1) * (B_ * H_) + (size_t)bi * H_ + ksub * 8);
#pragma unroll
        for (int kl = 0; kl < 16; ++kl) {
          f16x8 af = *(const f16x8*)(sh + kl * 32);
          acc0 = mfma16(af, wr0[kl], acc0);
          acc1 = mfma16(af, wr1[kl], acc1);
        }
        const int rowb = mt * 16 + ksub * 4;
#pragma unroll
        for (int r = 0; r < 4; ++r) {
          gbuf[kh * 2080 + (rowb + r) * 65 + colb]      = acc0[r];
          gbuf[kh * 2080 + (rowb + r) * 65 + colb + 16] = acc1[r];
        }
      }
      __syncthreads();
      if (s >= 1) {
        const float pi = gbuf[rb * 65 +      rh] + gbuf[2080 + rb * 65 +      rh] + bias_l[     rh];
        const float pf = gbuf[rb * 65 + 16 + rh] + gbuf[2080 + rb * 65 + 16 + rh] + bias_l[16 + rh];
        const float pg = gbuf[rb * 65 + 32 + rh] + gbuf[2080 + rb * 65 + 32 + rh] + bias_l[32 + rh];
        const float po = gbuf[rb * 65 + 48 + rh] + gbuf[2080 + rb * 65 + 48 + rh] + bias_l[48 + rh];
        const float ig = fast_sig(pi);
        const float fg = fast_sig(pf);
        const float gg = fast_tanh(pg);
        const float og = fast_sig(po);
        cst = fg * cst + ig * gg;
        const float hv = og * fast_tanh(cst);
        h2buf[(size_t)(t & 1) * (B_ * H_) + (size_t)rb * H_ + wgB * 16 + rh] = (f16)hv;
        __builtin_nontemporal_store(hv, h2seq + ((size_t)rb * T_ + t) * H_ + wgB * 16 + rh);
      }
      grid_barrier(flags, wg, (unsigned)(s + 1));
    }
  }
}

// o1[bt][128] = h2seq[bt][:] @ fcW^T + fcb   (K=512, f32, LDS-staged)
__global__ __launch_bounds__(256) void fc1_kernel(const float* __restrict__ h2s,
                                                  const float* __restrict__ fcW,
                                                  const float* __restrict__ fcb,
                                                  float* __restrict__ o1) {
  __shared__ float hT[64][44];
  __shared__ float wT[128][44];
  const int bt0 = blockIdx.x * 64;
  const int t = threadIdx.x;
  const int c4 = (t & 31) * 4;
  const int rowg = t >> 5;               // 0..7 -> 8 rows each
  float acc[8][4];
#pragma unroll
  for (int r = 0; r < 8; ++r)
#pragma unroll
    for (int j = 0; j < 4; ++j) acc[r][j] = 0.f;

  for (int kc = 0; kc < 16; ++kc) {
#pragma unroll
    for (int u = t; u < 512; u += 256) {
      const int r = u >> 3, k4 = u & 7;
      *(float4*)&hT[r][k4 * 4] = *(const float4*)(h2s + (size_t)(bt0 + r) * 512 + kc * 32 + k4 * 4);
    }
#pragma unroll
    for (int u = t; u < 1024; u += 256) {
      const int cc = u >> 3, k4 = u & 7;
      *(float4*)&wT[cc][k4 * 4] = *(const float4*)(fcW + (size_t)cc * 512 + kc * 32 + k4 * 4);
    }
    __syncthreads();
#pragma unroll
    for (int k4 = 0; k4 < 8; ++k4) {
      float4 w0 = *(float4*)&wT[c4 + 0][k4 * 4];
      float4 w1 = *(float4*)&wT[c4 + 1][k4 * 4];
      float4 w2 = *(float4*)&wT[c4 + 2][k4 * 4];
      float4 w3 = *(float4*)&wT[c4 + 3][k4 * 4];
#pragma unroll
      for (int rr = 0; rr < 8; ++rr) {
        float4 h = *(float4*)&hT[rowg * 8 + rr][k4 * 4];
        acc[rr][0] += h.x * w0.x + h.y * w0.y + h.z * w0.z + h.w * w0.w;
        acc[rr][1] += h.x * w1.x + h.y * w1.y + h.z * w1.z + h.w * w1.w;
        acc[rr][2] += h.x * w2.x + h.y * w2.y + h.z * w2.z + h.w * w2.w;
        acc[rr][3] += h.x * w3.x + h.y * w3.y + h.z * w3.z + h.w * w3.w;
      }
    }
    __syncthreads();
  }
#pragma unroll
  for (int rr = 0; rr < 8; ++rr) {
    const int r = bt0 + rowg * 8 + rr;
#pragma unroll
    for (int j = 0; j < 4; ++j)
      o1[(size_t)r * 128 + c4 + j] = acc[rr][j] + fcb[c4 + j];
  }
}

// out[bt][128] = o1[bt][:] @ fc2W^T + fc2b   (K=128)
__global__ __launch_bounds__(256) void fc2_kernel(const float* __restrict__ o1,
                                                  const float* __restrict__ fc2W,
                                                  const float* __restrict__ fc2b,
                                                  float* __restrict__ out) {
  __shared__ float oL[64][136];
  const int bt0 = blockIdx.x * 64;
  const int t = threadIdx.x;
#pragma unroll
  for (int u = t; u < 2048; u += 256) {
    const int r = u >> 5, k4 = u & 31;
    *(float4*)&oL[r][k4 * 4] = *(const float4*)(o1 + (size_t)(bt0 + r) * 128 + k4 * 4);
  }
  __syncthreads();
  const int c4 = (t & 31) * 4;
  const int rowg = t >> 5;
  float acc[8][4];
#pragma unroll
  for (int r = 0; r < 8; ++r)
#pragma unroll
    for (int j = 0; j < 4; ++j) acc[r][j] = 0.f;
#pragma unroll
  for (int k4 = 0; k4 < 32; ++k4) {
    float4 w0 = *(const float4*)(fc2W + (size_t)(c4 + 0) * 128 + k4 * 4);
    float4 w1 = *(const float4*)(fc2W + (size_t)(c4 + 1) * 128 + k4 * 4);
    float4 w2 = *(const float4*)(fc2W + (size_t)(c4 + 2) * 128 + k4 * 4);
    float4 w3 = *(const float4*)(fc2W + (size_t)(c4 + 3) * 128 + k4 * 4);
#pragma unroll
    for (int rr = 0; rr < 8; ++rr) {
      float4 h = *(float4*)&oL[rowg * 8 + rr][k4 * 4];
      acc[rr][0] += h.x * w0.x + h.y * w0.y + h.z * w0.z + h.w * w0.w;
      acc[rr][1] += h.x * w1.x + h.y * w1.y + h.z * w1.z + h.w * w1.w;
      acc[rr][2] += h.x * w2.x + h.y * w2.y + h.z * w2.z + h.w * w2.w;
      acc[rr][3] += h.x * w3.x + h.y * w3.y + h.z * w3.z + h.w * w3.w;
    }
  }
#pragma unroll
  for (int rr = 0; rr < 8; ++rr) {
    const int r = bt0 + rowg * 8 + rr;
#pragma unroll
    for (int j = 0; j < 4; ++j)
      out[(size_t)r * 128 + c4 + j] = acc[rr][j] + fc2b[c4 + j];
  }
}

extern "C" void kernel_launch(void* const* d_in, const int* in_sizes, int n_in,
                              void* d_out, int out_size, void* d_ws, size_t ws_size,
                              hipStream_t stream) {
  (void)in_sizes; (void)n_in; (void)out_size; (void)ws_size;
  const float* x    = (const float*)d_in[0];
  const float* Wih0 = (const float*)d_in[1];
  const float* Whh0 = (const float*)d_in[2];
  const float* bih0 = (const float*)d_in[3];
  const float* bhh0 = (const float*)d_in[4];
  const float* Wih1 = (const float*)d_in[5];
  const float* Whh1 = (const float*)d_in[6];
  const float* bih1 = (const float*)d_in[7];
  const float* bhh1 = (const float*)d_in[8];
  const float* fcW  = (const float*)d_in[9];
  const float* fcb  = (const float*)d_in[10];
  const float* fc2W = (const float*)d_in[11];
  const float* fc2b = (const float*)d_in[12];

  char* ws = (char*)d_ws;
  unsigned* flags = (unsigned*)(ws + OFF_FLAGS);
  f16* h1buf = (f16*)(ws + OFF_H1);
  f16* h2buf = (f16*)(ws + OFF_H2);
  f16* xT    = (f16*)(ws + OFF_XT);
  float* h2s = (float*)(ws + OFF_H2S);
  float* o1  = (float*)(ws + OFF_O1);
  float* out = (float*)d_out;

  // reset barrier flags + h-state ping-pong buffers (must be zero each call)
  hipMemsetAsync(ws, 0, OFF_H2 + 65536, stream);

  prep_xT<<<4096, 256, 0, stream>>>(x, xT);
  lstm_persist<<<NWG, 512, 0, stream>>>(Wih0, Whh0, bih0, bhh0,
                                        Wih1, Whh1, bih1, bhh1,
                                        xT, h1buf, h2buf, h2s, flags);
  fc1_kernel<<<512, 256, 0, stream>>>(h2s, fcW, fcb, o1);
  fc2_kernel<<<512, 256, 0, stream>>>(o1, fc2W, fc2b, out);
}

// Round 2
// 5213.493 us; speedup vs baseline: 1.8768x; 1.8768x over previous
//
#include <hip/hip_runtime.h>
#include <math.h>

typedef _Float16 f16;
typedef _Float16 f16x8 __attribute__((ext_vector_type(8)));
typedef _Float16 f16x4 __attribute__((ext_vector_type(4)));
typedef _Float16 f16x2 __attribute__((ext_vector_type(2)));
typedef float f32x4 __attribute__((ext_vector_type(4)));

#define B_ 32
#define T_ 1024
#define I_ 128
#define H_ 512

#define NWG 32          // one WG per 16 h-columns of each layer; 1 WG/CU
#define THR 512

// workspace layout (bytes)
#define OFF_FLAGS 0UL                   // 32 flags, 64B padded = 2048
#define OFF_H1S   4096UL                // f16 [1026][32][512] = 33,619,968 (slot k = h1[t=k-1], slot0 zeros)
#define OFF_H2S   33624064UL            // f16 [1025][32][512] = 33,587,200 (slot k = h2[t=k-1], slot0 zeros)
#define OFF_XT    67211264UL            // f16 [1024][32][128] = 8,388,608
#define OFF_O1    75599872UL            // f32 [32768][128]    = 16,777,216
// total: 92,377,088 bytes (< round-1 footprint)

__device__ inline f32x4 mfma16(f16x8 a, f16x8 b, f32x4 c) {
  return __builtin_amdgcn_mfma_f32_16x16x32_f16(a, b, c, 0, 0, 0);
}
__device__ inline float fast_sig(float x) { return 1.f / (1.f + __expf(-x)); }
__device__ inline float fast_tanh(float x) {
  float e = __expf(-2.f * fabsf(x));
  float t = (1.f - e) / (1.f + e);
  return x < 0.f ? -t : t;
}

// device-scope (cross-XCD) write-through store / cache-bypass load; no wbl2/inv needed
__device__ inline void st_coh_u32(unsigned* p, unsigned v) {
  asm volatile("global_store_dword %0, %1, off sc1" :: "v"(p), "v"(v) : "memory");
}
__device__ inline unsigned ld_coh_u32(const unsigned* p) {
  unsigned r;
  asm volatile("global_load_dword %0, %1, off sc1\n\ts_waitcnt vmcnt(0)"
               : "=v"(r) : "v"(p) : "memory");
  return r;
}

// LDS XOR-swizzle (T2-style): spreads the 16-row x stride-1KB ds_read_b128
// pattern over 8 16B slots -> 2-way conflicts (free, m136).
__device__ inline int swz_h(int b, int kbyte) { return b * 1024 + (kbyte ^ ((b & 7) << 4)); }
__device__ inline int swz_x(int b, int kbyte) { return b * 256  + (kbyte ^ ((b & 7) << 4)); }

// x[b][t][i] f32 -> xT[t][b][i] f16
__global__ __launch_bounds__(256) void prep_xT(const float* __restrict__ x, f16* __restrict__ xT) {
  const int idx = blockIdx.x * 256 + threadIdx.x;
  const int n4 = B_ * T_ * I_ / 4;
  if (idx < n4) {
    const int i4 = idx * 4;
    const int i  = i4 & (I_ - 1);
    const int tt = (i4 >> 7) & (T_ - 1);
    const int b  = i4 >> 17;
    float4 v = *(const float4*)(x + i4);
    f16x4 o;
    o[0] = (f16)v.x; o[1] = (f16)v.y; o[2] = (f16)v.z; o[3] = (f16)v.w;
    *(f16x4*)(xT + ((size_t)tt * B_ + b) * I_ + i) = o;
  }
}

// Persistent merged 2-layer LSTM, write-once h sequences, fence-free barrier.
// Step s (0..1024): L0 computes h1[t=s] (s<1024), L1 computes h2[t=s-1] (s>=1).
// WG wg owns h-cols [wg*16, wg*16+16) of BOTH layers. 8 waves: nt = wv&3 (16
// gate-cols), kh = wv>>2 (K half). Weights permanently in VGPRs.
__global__ __launch_bounds__(THR, 2) void lstm_persist(
    const float* __restrict__ Wih0, const float* __restrict__ Whh0,
    const float* __restrict__ bih0, const float* __restrict__ bhh0,
    const float* __restrict__ Wih1, const float* __restrict__ Whh1,
    const float* __restrict__ bih1, const float* __restrict__ bhh1,
    const f16* __restrict__ xT, f16* h1s, f16* h2s, unsigned* flags) {
  __shared__ int4 h1l4[2048];          // 32KB  h1[s-1] staged (swizzled)
  __shared__ int4 h2l4[2048];          // 32KB  h2[s-2] staged (swizzled)
  __shared__ int4 xl4[512];            // 8KB   x[s] staged (swizzled)
  __shared__ float g0[2 * 32 * 68];    // L0 gate partials [kh][32b][64c pad 68]
  __shared__ float g1[2 * 32 * 68];    // L1 gate partials
  __shared__ float bias0[64], bias1[64];

  const int tid  = threadIdx.x;
  const int wg   = blockIdx.x;
  const int lane = tid & 63;
  const int wv   = tid >> 6;           // 0..7
  const int nt   = wv & 3;             // ntile (16 gate-cols)
  const int kh   = wv >> 2;            // K half
  const int cfr  = lane & 15;
  const int ksub = lane >> 4;          // 0..3

  if (tid < 64) {
    const int g = tid >> 4, hc = tid & 15;
    const int row = g * 512 + wg * 16 + hc;
    bias0[tid] = bih0[row] + bhh0[row];
    bias1[tid] = bih1[row] + bhh1[row];
  }

  // ---- weight preload into VGPRs ----
  const int gc  = nt * 16 + cfr;       // 0..63
  const int row = (gc >> 4) * 512 + wg * 16 + (gc & 15);
  f16x8 wa[10];                        // L0: K=640 -> 20 ks, this wave 10
#pragma unroll
  for (int ksl = 0; ksl < 10; ++ksl) {
    const int k = (kh * 10 + ksl) * 32 + ksub * 8;
    const float* src = (k < I_) ? (Wih0 + (size_t)row * I_ + k)
                                : (Whh0 + (size_t)row * H_ + (k - I_));
    float4 v0 = *(const float4*)(src);
    float4 v1 = *(const float4*)(src + 4);
    f16x8 h;
    h[0] = (f16)v0.x; h[1] = (f16)v0.y; h[2] = (f16)v0.z; h[3] = (f16)v0.w;
    h[4] = (f16)v1.x; h[5] = (f16)v1.y; h[6] = (f16)v1.z; h[7] = (f16)v1.w;
    wa[ksl] = h;
  }
  f16x8 wb[16];                        // L1: K=1024 -> 32 ks, this wave 16
#pragma unroll
  for (int ksl = 0; ksl < 16; ++ksl) {
    const int k = (kh * 16 + ksl) * 32 + ksub * 8;
    const float* src = (k < H_) ? (Wih1 + (size_t)row * H_ + k)
                                : (Whh1 + (size_t)row * H_ + (k - H_));
    float4 v0 = *(const float4*)(src);
    float4 v1 = *(const float4*)(src + 4);
    f16x8 h;
    h[0] = (f16)v0.x; h[1] = (f16)v0.y; h[2] = (f16)v0.z; h[3] = (f16)v0.w;
    h[4] = (f16)v1.x; h[5] = (f16)v1.y; h[6] = (f16)v1.z; h[7] = (f16)v1.w;
    wb[ksl] = h;
  }

  float cst0 = 0.f, cst1 = 0.f;        // L0 cell state (threads 0..255)
  float dst0 = 0.f, dst1 = 0.f;        // L1 cell state (threads 256..511)
  const char* h1c = (const char*)h1l4;
  const char* h2c = (const char*)h2l4;
  const char* xc  = (const char*)xl4;

  __syncthreads();

  for (int s = 0; s <= T_; ++s) {
    // ---- stage phase: plain cold loads (write-once addresses) -> swizzled LDS ----
    {
      const int4* src = (const int4*)(h1s + (size_t)s * (B_ * H_));
#pragma unroll
      for (int r = 0; r < 4; ++r) {
        const int unit = r * 512 + tid;
        int4 v = src[unit];
        *(int4*)((char*)h1l4 + swz_h(unit >> 6, (unit & 63) * 16)) = v;
      }
    }
    if (s >= 1) {
      const int4* src = (const int4*)(h2s + (size_t)(s - 1) * (B_ * H_));
#pragma unroll
      for (int r = 0; r < 4; ++r) {
        const int unit = r * 512 + tid;
        int4 v = src[unit];
        *(int4*)((char*)h2l4 + swz_h(unit >> 6, (unit & 63) * 16)) = v;
      }
    }
    if (s < T_) {
      const int4* src = (const int4*)(xT + (size_t)s * (B_ * I_));
      int4 v = src[tid];
      *(int4*)((char*)xl4 + swz_x(tid >> 4, (tid & 15) * 16)) = v;
    }
    __syncthreads();

    // ---- MFMA phase (weights in VGPRs, A from LDS) ----
    if (s < T_) {                      // L0: h1[s] gates
      f32x4 a0 = {0.f, 0.f, 0.f, 0.f}, a1 = {0.f, 0.f, 0.f, 0.f};
#pragma unroll
      for (int ksl = 0; ksl < 10; ++ksl) {
        const int k = (kh * 10 + ksl) * 32 + ksub * 8;
        f16x8 af0, af1;
        if (k < I_) {
          af0 = *(const f16x8*)(xc + swz_x(cfr,      k * 2));
          af1 = *(const f16x8*)(xc + swz_x(16 + cfr, k * 2));
        } else {
          af0 = *(const f16x8*)(h1c + swz_h(cfr,      (k - I_) * 2));
          af1 = *(const f16x8*)(h1c + swz_h(16 + cfr, (k - I_) * 2));
        }
        a0 = mfma16(af0, wa[ksl], a0);
        a1 = mfma16(af1, wa[ksl], a1);
      }
      const int base = kh * 2176 + (ksub * 4) * 68 + nt * 16 + cfr;
#pragma unroll
      for (int r = 0; r < 4; ++r) {
        g0[base + r * 68]            = a0[r];
        g0[base + 16 * 68 + r * 68]  = a1[r];
      }
    }
    if (s >= 1) {                      // L1: h2[s-1] gates, input [h1[s-1] | h2[s-2]]
      f32x4 a0 = {0.f, 0.f, 0.f, 0.f}, a1 = {0.f, 0.f, 0.f, 0.f};
#pragma unroll
      for (int ksl = 0; ksl < 16; ++ksl) {
        const int k = (kh * 16 + ksl) * 32 + ksub * 8;
        f16x8 af0, af1;
        if (k < H_) {
          af0 = *(const f16x8*)(h1c + swz_h(cfr,      k * 2));
          af1 = *(const f16x8*)(h1c + swz_h(16 + cfr, k * 2));
        } else {
          af0 = *(const f16x8*)(h2c + swz_h(cfr,      (k - H_) * 2));
          af1 = *(const f16x8*)(h2c + swz_h(16 + cfr, (k - H_) * 2));
        }
        a0 = mfma16(af0, wb[ksl], a0);
        a1 = mfma16(af1, wb[ksl], a1);
      }
      const int base = kh * 2176 + (ksub * 4) * 68 + nt * 16 + cfr;
#pragma unroll
      for (int r = 0; r < 4; ++r) {
        g1[base + r * 68]            = a0[r];
        g1[base + 16 * 68 + r * 68]  = a1[r];
      }
    }
    __syncthreads();

    // ---- pointwise + coherent h store (f16x2 packed, sc1 write-through) ----
    if (s < T_ && tid < 256) {         // L0
      const int rb = tid >> 3, hp = tid & 7;
      const float* gr = g0 + rb * 68;
      float hv[2];
#pragma unroll
      for (int cc = 0; cc < 2; ++cc) {
        const int c = 2 * hp + cc;
        const float pi = gr[c]           + gr[2176 + c]           + bias0[c];
        const float pf = gr[16 + c]      + gr[2176 + 16 + c]      + bias0[16 + c];
        const float pg = gr[32 + c]      + gr[2176 + 32 + c]      + bias0[32 + c];
        const float po = gr[48 + c]      + gr[2176 + 48 + c]      + bias0[48 + c];
        const float ig = fast_sig(pi), fg = fast_sig(pf);
        const float gg = fast_tanh(pg), og = fast_sig(po);
        const float cprev = cc ? cst1 : cst0;
        const float cnew = fg * cprev + ig * gg;
        if (cc) cst1 = cnew; else cst0 = cnew;
        hv[cc] = og * fast_tanh(cnew);
      }
      f16x2 pk; pk[0] = (f16)hv[0]; pk[1] = (f16)hv[1];
      unsigned* dst = (unsigned*)(h1s + (size_t)(s + 1) * (B_ * H_) + rb * H_ + wg * 16 + 2 * hp);
      st_coh_u32(dst, __builtin_bit_cast(unsigned, pk));
    }
    if (s >= 1 && tid >= 256) {        // L1
      const int t2 = tid - 256;
      const int rb = t2 >> 3, hp = t2 & 7;
      const float* gr = g1 + rb * 68;
      float hv[2];
#pragma unroll
      for (int cc = 0; cc < 2; ++cc) {
        const int c = 2 * hp + cc;
        const float pi = gr[c]           + gr[2176 + c]           + bias1[c];
        const float pf = gr[16 + c]      + gr[2176 + 16 + c]      + bias1[16 + c];
        const float pg = gr[32 + c]      + gr[2176 + 32 + c]      + bias1[32 + c];
        const float po = gr[48 + c]      + gr[2176 + 48 + c]      + bias1[48 + c];
        const float ig = fast_sig(pi), fg = fast_sig(pf);
        const float gg = fast_tanh(pg), og = fast_sig(po);
        const float cprev = cc ? dst1 : dst0;
        const float cnew = fg * cprev + ig * gg;
        if (cc) dst1 = cnew; else dst0 = cnew;
        hv[cc] = og * fast_tanh(cnew);
      }
      f16x2 pk; pk[0] = (f16)hv[0]; pk[1] = (f16)hv[1];
      unsigned* dst = (unsigned*)(h2s + (size_t)s * (B_ * H_) + rb * H_ + wg * 16 + 2 * hp);
      st_coh_u32(dst, __builtin_bit_cast(unsigned, pk));
    }

    // ---- fence-free grid barrier ----
    asm volatile("s_waitcnt vmcnt(0)" ::: "memory");  // drain this wave's sc1 stores
    __syncthreads();                                   // all waves' stores at coherence point
    if (tid == 0) st_coh_u32(flags + wg * 16, (unsigned)(s + 1));
    if (tid < 64) {
      const unsigned tgt = (unsigned)(s + 1);
      const unsigned* fp = flags + (tid < NWG ? tid : 0) * 16;
      const bool active = tid < NWG;
      for (;;) {
        unsigned v = ld_coh_u32(fp);
        if (!active) v = tgt;
        if (__all((int)(v >= tgt))) break;
        __builtin_amdgcn_s_sleep(1);
      }
    }
    __syncthreads();
    __builtin_amdgcn_sched_barrier(0);
  }
}

// o1[bt][128] = h2seq(f16)[bt][:] @ fcW^T + fcb   (K=512)
__global__ __launch_bounds__(256) void fc1_kernel(const f16* __restrict__ h2s,
                                                  const float* __restrict__ fcW,
                                                  const float* __restrict__ fcb,
                                                  float* __restrict__ o1) {
  __shared__ float hT[64][36];
  __shared__ float wT[128][36];
  const int bt0 = blockIdx.x * 64;
  const int bb  = bt0 >> 10;           // batch (constant per block: 64 | 1024)
  const int t0  = bt0 & 1023;
  const int t = threadIdx.x;
  const int c4 = (t & 31) * 4;
  const int rowg = t >> 5;
  float acc[8][4];
#pragma unroll
  for (int r = 0; r < 8; ++r)
#pragma unroll
    for (int j = 0; j < 4; ++j) acc[r][j] = 0.f;

  for (int kc = 0; kc < 16; ++kc) {
    {
      const int r = t >> 2, q = t & 3;
      const f16x8 v = *(const f16x8*)(h2s + ((size_t)(t0 + r + 1) * B_ + bb) * 512 + kc * 32 + q * 8);
#pragma unroll
      for (int j = 0; j < 8; ++j) hT[r][q * 8 + j] = (float)v[j];
    }
#pragma unroll
    for (int u = t; u < 1024; u += 256) {
      const int cc = u >> 3, k4 = u & 7;
      *(float4*)&wT[cc][k4 * 4] = *(const float4*)(fcW + (size_t)cc * 512 + kc * 32 + k4 * 4);
    }
    __syncthreads();
#pragma unroll
    for (int k4 = 0; k4 < 8; ++k4) {
      float4 w0 = *(float4*)&wT[c4 + 0][k4 * 4];
      float4 w1 = *(float4*)&wT[c4 + 1][k4 * 4];
      float4 w2 = *(float4*)&wT[c4 + 2][k4 * 4];
      float4 w3 = *(float4*)&wT[c4 + 3][k4 * 4];
#pragma unroll
      for (int rr = 0; rr < 8; ++rr) {
        float4 h = *(float4*)&hT[rowg * 8 + rr][k4 * 4];
        acc[rr][0] += h.x * w0.x + h.y * w0.y + h.z * w0.z + h.w * w0.w;
        acc[rr][1] += h.x * w1.x + h.y * w1.y + h.z * w1.z + h.w * w1.w;
        acc[rr][2] += h.x * w2.x + h.y * w2.y + h.z * w2.z + h.w * w2.w;
        acc[rr][3] += h.x * w3.x + h.y * w3.y + h.z * w3.z + h.w * w3.w;
      }
    }
    __syncthreads();
  }
#pragma unroll
  for (int rr = 0; rr < 8; ++rr) {
    const int r = bt0 + rowg * 8 + rr;
#pragma unroll
    for (int j = 0; j < 4; ++j)
      o1[(size_t)r * 128 + c4 + j] = acc[rr][j] + fcb[c4 + j];
  }
}

// out[bt][128] = o1[bt][:] @ fc2W^T + fc2b   (K=128)
__global__ __launch_bounds__(256) void fc2_kernel(const float* __restrict__ o1,
                                                  const float* __restrict__ fc2W,
                                                  const float* __restrict__ fc2b,
                                                  float* __restrict__ out) {
  __shared__ float oL[64][136];
  const int bt0 = blockIdx.x * 64;
  const int t = threadIdx.x;
#pragma unroll
  for (int u = t; u < 2048; u += 256) {
    const int r = u >> 5, k4 = u & 31;
    *(float4*)&oL[r][k4 * 4] = *(const float4*)(o1 + (size_t)(bt0 + r) * 128 + k4 * 4);
  }
  __syncthreads();
  const int c4 = (t & 31) * 4;
  const int rowg = t >> 5;
  float acc[8][4];
#pragma unroll
  for (int r = 0; r < 8; ++r)
#pragma unroll
    for (int j = 0; j < 4; ++j) acc[r][j] = 0.f;
#pragma unroll
  for (int k4 = 0; k4 < 32; ++k4) {
    float4 w0 = *(const float4*)(fc2W + (size_t)(c4 + 0) * 128 + k4 * 4);
    float4 w1 = *(const float4*)(fc2W + (size_t)(c4 + 1) * 128 + k4 * 4);
    float4 w2 = *(const float4*)(fc2W + (size_t)(c4 + 2) * 128 + k4 * 4);
    float4 w3 = *(const float4*)(fc2W + (size_t)(c4 + 3) * 128 + k4 * 4);
#pragma unroll
    for (int rr = 0; rr < 8; ++rr) {
      float4 h = *(float4*)&oL[rowg * 8 + rr][k4 * 4];
      acc[rr][0] += h.x * w0.x + h.y * w0.y + h.z * w0.z + h.w * w0.w;
      acc[rr][1] += h.x * w1.x + h.y * w1.y + h.z * w1.z + h.w * w1.w;
      acc[rr][2] += h.x * w2.x + h.y * w2.y + h.z * w2.z + h.w * w2.w;
      acc[rr][3] += h.x * w3.x + h.y * w3.y + h.z * w3.z + h.w * w3.w;
    }
  }
#pragma unroll
  for (int rr = 0; rr < 8; ++rr) {
    const int r = bt0 + rowg * 8 + rr;
#pragma unroll
    for (int j = 0; j < 4; ++j)
      out[(size_t)r * 128 + c4 + j] = acc[rr][j] + fc2b[c4 + j];
  }
}

extern "C" void kernel_launch(void* const* d_in, const int* in_sizes, int n_in,
                              void* d_out, int out_size, void* d_ws, size_t ws_size,
                              hipStream_t stream) {
  (void)in_sizes; (void)n_in; (void)out_size; (void)ws_size;
  const float* x    = (const float*)d_in[0];
  const float* Wih0 = (const float*)d_in[1];
  const float* Whh0 = (const float*)d_in[2];
  const float* bih0 = (const float*)d_in[3];
  const float* bhh0 = (const float*)d_in[4];
  const float* Wih1 = (const float*)d_in[5];
  const float* Whh1 = (const float*)d_in[6];
  const float* bih1 = (const float*)d_in[7];
  const float* bhh1 = (const float*)d_in[8];
  const float* fcW  = (const float*)d_in[9];
  const float* fcb  = (const float*)d_in[10];
  const float* fc2W = (const float*)d_in[11];
  const float* fc2b = (const float*)d_in[12];

  char* ws = (char*)d_ws;
  unsigned* flags = (unsigned*)(ws + OFF_FLAGS);
  f16* h1s = (f16*)(ws + OFF_H1S);
  f16* h2s = (f16*)(ws + OFF_H2S);
  f16* xT  = (f16*)(ws + OFF_XT);
  float* o1 = (float*)(ws + OFF_O1);
  float* out = (float*)d_out;

  // per-call init: flags = 0, h1[t=-1] = 0, h2[t=-1] = 0
  hipMemsetAsync(ws + OFF_FLAGS, 0, 2048, stream);
  hipMemsetAsync(ws + OFF_H1S, 0, 32768, stream);
  hipMemsetAsync(ws + OFF_H2S, 0, 32768, stream);

  prep_xT<<<4096, 256, 0, stream>>>(x, xT);
  lstm_persist<<<NWG, THR, 0, stream>>>(Wih0, Whh0, bih0, bhh0,
                                        Wih1, Whh1, bih1, bhh1,
                                        xT, h1s, h2s, flags);
  fc1_kernel<<<512, 256, 0, stream>>>(h2s, fcW, fcb, o1);
  fc2_kernel<<<512, 256, 0, stream>>>(o1, fc2W, fc2b, out);
}